// Round 2
// baseline (2094.436 us; speedup 1.0000x reference)
//
#include <hip/hip_runtime.h>

#define N_SAMPLES 65536
#define K_CENT    1024
#define DIM       512

#define BM 64
#define BN 64
#define BD 32
#define LDST 68   // padded LDS stride: 68*4B = 272B, 16B-aligned rows, breaks 8-way write conflicts
#define TAU 0.125f  // near-tie gap threshold; fp32 noise bound ~2e-3 -> 60x margin

// ---------------- c2[k] = sum(centers[k]^2) ----------------
__global__ __launch_bounds__(256) void c2_kernel(const float* __restrict__ centers,
                                                 float* __restrict__ c2) {
    int wave = threadIdx.x >> 6;
    int lane = threadIdx.x & 63;
    int k = blockIdx.x * 4 + wave;
    if (k >= K_CENT) return;
    const float* row = centers + (size_t)k * DIM;
    float s = 0.f;
    #pragma unroll
    for (int base = 0; base < DIM; base += 256) {
        float4 v = *(const float4*)(row + base + lane * 4);
        s += v.x * v.x + v.y * v.y + v.z * v.z + v.w * v.w;
    }
    for (int off = 32; off; off >>= 1) s += __shfl_down(s, off);
    if (lane == 0) c2[k] = s;
}

// ---------------- fused GEMM + min/argmin + second-best tracking ----------------
__global__ __launch_bounds__(256) void assign_kernel(
    const float* __restrict__ A,      // embedded [N,D]
    const float* __restrict__ B,      // centers  [K,D]
    const float* __restrict__ c2,
    float* __restrict__ out_loss,
    float* __restrict__ out_s,
    int* __restrict__ s_idx,
    int* __restrict__ flag_cnt,
    int* __restrict__ flagged)
{
    __shared__ float As[BD][LDST];    // transposed: As[d][m]
    __shared__ float Bs[BD][LDST];    // transposed: Bs[d][k]
    __shared__ float Ss[16][BM];      // second-best staging
    __shared__ float minv[BM];

    const int tid = threadIdx.x;
    const int tm = tid & 15;
    const int tn = tid >> 4;
    const int m0 = blockIdx.x * BM;

    float bestv[4], secv[4];
    int   besti[4];
    #pragma unroll
    for (int i = 0; i < 4; ++i) { bestv[i] = 3.4e38f; secv[i] = 3.4e38f; besti[i] = 0; }

    for (int kt = 0; kt < K_CENT / BN; ++kt) {
        float acc[4][4];
        #pragma unroll
        for (int i = 0; i < 4; ++i)
            #pragma unroll
            for (int j = 0; j < 4; ++j) acc[i][j] = 0.f;

        for (int dt = 0; dt < DIM / BD; ++dt) {
            __syncthreads();
            #pragma unroll
            for (int it = 0; it < 2; ++it) {
                int l = tid + it * 256;
                int row = l >> 3, qd = l & 7;
                float4 va = *(const float4*)(A + (size_t)(m0 + row) * DIM + dt * BD + qd * 4);
                As[qd * 4 + 0][row] = va.x;
                As[qd * 4 + 1][row] = va.y;
                As[qd * 4 + 2][row] = va.z;
                As[qd * 4 + 3][row] = va.w;
                float4 vb = *(const float4*)(B + (size_t)(kt * BN + row) * DIM + dt * BD + qd * 4);
                Bs[qd * 4 + 0][row] = vb.x;
                Bs[qd * 4 + 1][row] = vb.y;
                Bs[qd * 4 + 2][row] = vb.z;
                Bs[qd * 4 + 3][row] = vb.w;
            }
            __syncthreads();
            #pragma unroll
            for (int d = 0; d < BD; ++d) {
                const float4 av = *(const float4*)&As[d][tm * 4];
                const float4 bv = *(const float4*)&Bs[d][tn * 4];
                float a[4] = {av.x, av.y, av.z, av.w};
                float b[4] = {bv.x, bv.y, bv.z, bv.w};
                #pragma unroll
                for (int i = 0; i < 4; ++i)
                    #pragma unroll
                    for (int j = 0; j < 4; ++j) acc[i][j] += a[i] * b[j];
            }
        }
        #pragma unroll
        for (int j = 0; j < 4; ++j) {
            int k = kt * BN + tn * 4 + j;
            float c2k = c2[k];
            #pragma unroll
            for (int i = 0; i < 4; ++i) {
                float v = c2k - 2.0f * acc[i][j];
                if (v < bestv[i]) { secv[i] = bestv[i]; bestv[i] = v; besti[i] = k; }
                else if (v < secv[i]) secv[i] = v;
            }
        }
    }

    // cross-thread (best, idx, second) merge over the 16 tn groups
    __syncthreads();
    float (*rv)[BM] = (float (*)[BM])As;
    int   (*ri)[BM] = (int   (*)[BM])Bs;
    #pragma unroll
    for (int i = 0; i < 4; ++i) {
        rv[tn][tm * 4 + i] = bestv[i];
        ri[tn][tm * 4 + i] = besti[i];
        Ss[tn][tm * 4 + i] = secv[i];
    }
    __syncthreads();
    if (tid < BM) {
        float bv = rv[0][tid];
        int   bi = ri[0][tid];
        float sv = Ss[0][tid];
        #pragma unroll
        for (int t = 1; t < 16; ++t) {
            float v  = rv[t][tid];
            int   ii = ri[t][tid];
            float s2 = Ss[t][tid];
            if (v < bv || (v == bv && ii < bi)) { sv = fminf(bv, s2); bv = v; bi = ii; }
            else sv = fminf(sv, v);
        }
        int n = m0 + tid;
        s_idx[n] = bi;
        out_s[n] = (float)bi;
        if (sv - bv < TAU) {                 // near-tie: queue for fp64 re-check
            int p = atomicAdd(flag_cnt, 1);
            flagged[p] = n;
        }
        minv[tid] = bv;
    }
    __syncthreads();
    if (tid == 0) {
        float s = 0.f;
        for (int i = 0; i < BM; ++i) s += minv[i];
        atomicAdd(out_loss, s * (1.0f / N_SAMPLES));
    }
}

// ---------------- exact fp64 re-check of flagged near-tie samples ----------------
__global__ __launch_bounds__(256) void refine_kernel(
    const float* __restrict__ emb,
    const float* __restrict__ cen,
    const int* __restrict__ flag_cnt,
    const int* __restrict__ flagged,
    int* __restrict__ s_idx,
    float* __restrict__ out_s)
{
    __shared__ float e_sh[DIM];
    __shared__ double rvd[256];
    __shared__ int rid[256];
    const int t = threadIdx.x;
    const int cnt = *flag_cnt;
    for (int idx = blockIdx.x; idx < cnt; idx += gridDim.x) {
        int n = flagged[idx];
        __syncthreads();
        ((float2*)e_sh)[t] = ((const float2*)(emb + (size_t)n * DIM))[t];
        __syncthreads();
        double bestd = 1e300;
        int bestk = 0;
        #pragma unroll
        for (int j = 0; j < 4; ++j) {
            int k = t * 4 + j;                       // k ascending per thread
            const float* crow = cen + (size_t)k * DIM;
            double acc = 0.0;
            for (int d = 0; d < DIM; d += 4) {
                float4 cv = *(const float4*)(crow + d);
                double d0 = (double)e_sh[d + 0] - (double)cv.x;
                double d1 = (double)e_sh[d + 1] - (double)cv.y;
                double d2 = (double)e_sh[d + 2] - (double)cv.z;
                double d3 = (double)e_sh[d + 3] - (double)cv.w;
                acc += d0 * d0 + d1 * d1 + d2 * d2 + d3 * d3;
            }
            if (acc < bestd) { bestd = acc; bestk = k; }
        }
        rvd[t] = bestd; rid[t] = bestk;
        __syncthreads();
        for (int off = 128; off; off >>= 1) {
            if (t < off) {
                double v = rvd[t + off]; int ii = rid[t + off];
                if (v < rvd[t] || (v == rvd[t] && ii < rid[t])) { rvd[t] = v; rid[t] = ii; }
            }
            __syncthreads();
        }
        if (t == 0) { s_idx[n] = rid[0]; out_s[n] = (float)rid[0]; }
    }
}

// ---------------- histogram from (refined) assignments ----------------
__global__ void hist_kernel(const int* __restrict__ s_idx, int* __restrict__ hist) {
    int n = blockIdx.x * blockDim.x + threadIdx.x;
    if (n < N_SAMPLES) atomicAdd(&hist[s_idx[n]], 1);
}

// ---------------- prefix sum over histogram ----------------
__global__ void scan_kernel(const int* __restrict__ hist,
                            int* __restrict__ offsets,
                            int* __restrict__ cursor,
                            const int* __restrict__ count_in,
                            float* __restrict__ out_count) {
    __shared__ int sbuf[K_CENT];
    int t = threadIdx.x;
    int v = hist[t];
    sbuf[t] = v;
    __syncthreads();
    for (int off = 1; off < K_CENT; off <<= 1) {
        int x = (t >= off) ? sbuf[t - off] : 0;
        __syncthreads();
        sbuf[t] += x;
        __syncthreads();
    }
    int incl = sbuf[t];
    int excl = incl - v;
    offsets[t] = excl;
    cursor[t]  = excl;
    out_count[t] = (float)(count_in[t] + v);
    if (t == K_CENT - 1) offsets[K_CENT] = incl;
}

// ---------------- scatter sample ids into cluster buckets ----------------
__global__ void scatter_kernel(const int* __restrict__ s_idx,
                               int* __restrict__ cursor,
                               int* __restrict__ order) {
    int n = blockIdx.x * blockDim.x + threadIdx.x;
    if (n < N_SAMPLES) {
        int c = s_idx[n];
        int pos = atomicAdd(&cursor[c], 1);
        order[pos] = n;
    }
}

// ---------------- segment mean + centers update + e2 part of loss ----------------
__global__ __launch_bounds__(256) void gather_kernel(
    const float* __restrict__ emb,
    const float* __restrict__ centers,
    const int* __restrict__ count_in,
    const int* __restrict__ offsets,
    const int* __restrict__ order,
    float* __restrict__ out_centers,
    float* __restrict__ out_loss)
{
    int k = blockIdx.x;
    int t = threadIdx.x;
    int start = offsets[k], end = offsets[k + 1];
    float2 acc = {0.f, 0.f};
    float ssq = 0.f;
    for (int r = start; r < end; ++r) {
        int n = order[r];
        float2 e = *(const float2*)(emb + (size_t)n * DIM + t * 2);
        acc.x += e.x; acc.y += e.y;
        ssq += e.x * e.x + e.y * e.y;
    }
    float cnt = (float)count_in[k];
    float tot = cnt + (float)(end - start);
    float2 c = *(const float2*)(centers + (size_t)k * DIM + t * 2);
    float2 o;
    o.x = (cnt * c.x + acc.x) / tot;
    o.y = (cnt * c.y + acc.y) / tot;
    *(float2*)(out_centers + (size_t)k * DIM + t * 2) = o;

    for (int off = 32; off; off >>= 1) ssq += __shfl_down(ssq, off);
    __shared__ float wsum[4];
    int lane = t & 63, wv = t >> 6;
    if (lane == 0) wsum[wv] = ssq;
    __syncthreads();
    if (t == 0) {
        float s2 = wsum[0] + wsum[1] + wsum[2] + wsum[3];
        atomicAdd(out_loss, s2 * (1.0f / N_SAMPLES));
    }
}

extern "C" void kernel_launch(void* const* d_in, const int* in_sizes, int n_in,
                              void* d_out, int out_size, void* d_ws, size_t ws_size,
                              hipStream_t stream) {
    const float* emb = (const float*)d_in[0];
    const float* cen = (const float*)d_in[1];
    const int*   cnt = (const int*)d_in[2];

    float* out = (float*)d_out;
    float* out_loss    = out;
    float* out_s       = out + 1;
    float* out_centers = out + 1 + N_SAMPLES;
    float* out_count   = out + 1 + N_SAMPLES + (size_t)K_CENT * DIM;

    int* wsi      = (int*)d_ws;
    int* hist     = wsi;                    // 1024
    int* offsets  = wsi + 1024;             // 1025
    int* cursor   = wsi + 2064;             // 1024
    int* s_idx    = wsi + 4096;             // 65536
    int* order    = wsi + 69632;            // 65536
    float* c2     = (float*)(wsi + 135168); // 1024
    int* flag_cnt = wsi + 136192;           // 1
    int* flagged  = wsi + 136448;           // 65536

    hipMemsetAsync(hist, 0, K_CENT * sizeof(int), stream);
    hipMemsetAsync(out_loss, 0, sizeof(float), stream);
    hipMemsetAsync(flag_cnt, 0, sizeof(int), stream);

    c2_kernel<<<K_CENT / 4, 256, 0, stream>>>(cen, c2);
    assign_kernel<<<N_SAMPLES / BM, 256, 0, stream>>>(emb, cen, c2, out_loss, out_s,
                                                      s_idx, flag_cnt, flagged);
    refine_kernel<<<256, 256, 0, stream>>>(emb, cen, flag_cnt, flagged, s_idx, out_s);
    hist_kernel<<<(N_SAMPLES + 255) / 256, 256, 0, stream>>>(s_idx, hist);
    scan_kernel<<<1, K_CENT, 0, stream>>>(hist, offsets, cursor, cnt, out_count);
    scatter_kernel<<<(N_SAMPLES + 255) / 256, 256, 0, stream>>>(s_idx, cursor, order);
    gather_kernel<<<K_CENT, 256, 0, stream>>>(emb, cen, cnt, offsets, order, out_centers, out_loss);
}

// Round 4
// 1109.148 us; speedup vs baseline: 1.8883x; 1.8883x over previous
//
#include <hip/hip_runtime.h>

#define N_SAMPLES 65536
#define K_CENT    1024
#define DIM       512
#define TAU 0.125f   // bf16-split dist error <= ~0.01 worst-case -> 10x+ margin

typedef __attribute__((ext_vector_type(8))) short  short8;
typedef __attribute__((ext_vector_type(4))) float  float4v;
typedef __attribute__((ext_vector_type(4))) unsigned short ushort4v;

__device__ inline unsigned short f2bf(float x) {           // RTNE fp32 -> bf16
    unsigned u = __builtin_bit_cast(unsigned, x);
    unsigned r = u + 0x7FFFu + ((u >> 16) & 1u);
    return (unsigned short)(r >> 16);
}
__device__ inline float bf2f(unsigned short h) {
    return __builtin_bit_cast(float, ((unsigned)h) << 16);
}

// ---------------- c2[k] = sum(centers[k]^2) ----------------
__global__ __launch_bounds__(256) void c2_kernel(const float* __restrict__ centers,
                                                 float* __restrict__ c2) {
    int wave = threadIdx.x >> 6, lane = threadIdx.x & 63;
    int k = blockIdx.x * 4 + wave;
    const float* row = centers + (size_t)k * DIM;
    float s = 0.f;
    #pragma unroll
    for (int base = 0; base < DIM; base += 256) {
        float4 v = *(const float4*)(row + base + lane * 4);
        s += v.x * v.x + v.y * v.y + v.z * v.z + v.w * v.w;
    }
    for (int off = 32; off; off >>= 1) s += __shfl_down(s, off);
    if (lane == 0) c2[k] = s;
}

// ---------------- split centers into bf16 hi/lo ----------------
__global__ __launch_bounds__(256) void bsplit_kernel(const float* __restrict__ cen,
                                                     unsigned short* __restrict__ Bh,
                                                     unsigned short* __restrict__ Bl) {
    int idx = blockIdx.x * 256 + threadIdx.x;   // float4 index; grid 512 covers 1024*512
    float4 v = ((const float4*)cen)[idx];
    float f[4] = {v.x, v.y, v.z, v.w};
    ushort4v h, l;
    #pragma unroll
    for (int e = 0; e < 4; ++e) {
        unsigned short hh = f2bf(f[e]);
        h[e] = hh;
        l[e] = f2bf(f[e] - bf2f(hh));
    }
    *(ushort4v*)(Bh + (size_t)idx * 4) = h;
    *(ushort4v*)(Bl + (size_t)idx * 4) = l;
}

// ---------------- MFMA assign: fused 3-term bf16-split GEMM + argmin ----------------
#define LDSA 40   // padded row stride (elements): 32 data + 8 pad; 2-way bank alias = free
__global__ __launch_bounds__(256) void assign_mfma(
    const float* __restrict__ A,            // embedded [N,D]
    const unsigned short* __restrict__ Bh,  // centers hi bf16 [K,D]
    const unsigned short* __restrict__ Bl,  // centers lo bf16 [K,D]
    const float* __restrict__ c2,
    float* __restrict__ out_loss,
    float* __restrict__ out_s,
    int* __restrict__ s_idx,
    int* __restrict__ flag_cnt,
    int* __restrict__ flagged)
{
    __shared__ unsigned short Ah[128 * LDSA];
    __shared__ unsigned short Al[128 * LDSA];
    __shared__ float st_best[128];
    __shared__ float st_sec[128];
    __shared__ int   st_idx[128];

    const int tid  = threadIdx.x;
    const int w    = tid >> 6;        // wave 0..3: rows w*32..w*32+31
    const int lane = tid & 63;
    const int quad = lane >> 4;
    const int l15  = lane & 15;
    const int m0   = blockIdx.x * 128;

    if (tid < 128) { st_best[tid] = 3.4e38f; st_sec[tid] = 3.4e38f; st_idx[tid] = 0; }

    const int r0 = tid >> 2, q = tid & 3;

    for (int nt = 0; nt < 8; ++nt) {
        float4v acc[16];
        #pragma unroll
        for (int z = 0; z < 16; ++z) acc[z] = (float4v){0.f, 0.f, 0.f, 0.f};

        for (int ks = 0; ks < 16; ++ks) {
            __syncthreads();
            // stage A tile 128x32 fp32 -> bf16 hi/lo in LDS
            #pragma unroll
            for (int half = 0; half < 2; ++half) {
                int rr = r0 + half * 64;
                const float* src = A + (size_t)(m0 + rr) * DIM + ks * 32 + q * 8;
                float4 v0 = *(const float4*)src;
                float4 v1 = *(const float4*)(src + 4);
                float f[8] = {v0.x, v0.y, v0.z, v0.w, v1.x, v1.y, v1.z, v1.w};
                short8 hi, lo;
                #pragma unroll
                for (int e = 0; e < 8; ++e) {
                    unsigned short hh = f2bf(f[e]);
                    hi[e] = (short)hh;
                    lo[e] = (short)f2bf(f[e] - bf2f(hh));
                }
                *(short8*)&Ah[rr * LDSA + q * 8] = hi;
                *(short8*)&Al[rr * LDSA + q * 8] = lo;
            }
            __syncthreads();

            // A fragments from LDS (2-way bank aliasing = free)
            short8 ah[2], al[2];
            #pragma unroll
            for (int i = 0; i < 2; ++i) {
                int row = w * 32 + i * 16 + l15;
                ah[i] = *(const short8*)&Ah[row * LDSA + quad * 8];
                al[i] = *(const short8*)&Al[row * LDSA + quad * 8];
            }
            // B fragments register-direct (L1/L2-resident), j in halves of 4
            #pragma unroll
            for (int jh = 0; jh < 2; ++jh) {
                short8 bh[4], bl[4];
                #pragma unroll
                for (int j4 = 0; j4 < 4; ++j4) {
                    size_t off = (size_t)(nt * 128 + (jh * 4 + j4) * 16 + l15) * DIM
                               + ks * 32 + quad * 8;
                    bh[j4] = *(const short8*)(Bh + off);
                    bl[j4] = *(const short8*)(Bl + off);
                }
                #pragma unroll
                for (int j4 = 0; j4 < 4; ++j4)
                    #pragma unroll
                    for (int i = 0; i < 2; ++i)
                        acc[i * 8 + jh * 4 + j4] = __builtin_amdgcn_mfma_f32_16x16x32_bf16(
                            ah[i], bh[j4], acc[i * 8 + jh * 4 + j4], 0, 0, 0);
                #pragma unroll
                for (int j4 = 0; j4 < 4; ++j4)
                    #pragma unroll
                    for (int i = 0; i < 2; ++i)
                        acc[i * 8 + jh * 4 + j4] = __builtin_amdgcn_mfma_f32_16x16x32_bf16(
                            ah[i], bl[j4], acc[i * 8 + jh * 4 + j4], 0, 0, 0);
                #pragma unroll
                for (int j4 = 0; j4 < 4; ++j4)
                    #pragma unroll
                    for (int i = 0; i < 2; ++i)
                        acc[i * 8 + jh * 4 + j4] = __builtin_amdgcn_mfma_f32_16x16x32_bf16(
                            al[i], bh[j4], acc[i * 8 + jh * 4 + j4], 0, 0, 0);
            }
        }

        // epilogue: dist = c2[n] - 2*cross; per-lane best over j, butterfly over l15
        float c2v[8];
        #pragma unroll
        for (int j = 0; j < 8; ++j) c2v[j] = c2[nt * 128 + j * 16 + l15];
        #pragma unroll
        for (int i = 0; i < 2; ++i)
            #pragma unroll
            for (int reg = 0; reg < 4; ++reg) {
                float bv = 3.4e38f, sv = 3.4e38f; int bi = 0;
                #pragma unroll
                for (int j = 0; j < 8; ++j) {
                    float v = c2v[j] - 2.0f * acc[i * 8 + j][reg];
                    int n = nt * 128 + j * 16 + l15;
                    if (v < bv) { sv = bv; bv = v; bi = n; }
                    else if (v < sv) sv = v;
                }
                #pragma unroll
                for (int mask = 1; mask < 16; mask <<= 1) {
                    float ob = __shfl_xor(bv, mask);
                    float os = __shfl_xor(sv, mask);
                    int   oi = __shfl_xor(bi, mask);
                    float ns = fminf(fminf(sv, os), fmaxf(bv, ob));
                    if (ob < bv || (ob == bv && oi < bi)) { bv = ob; bi = oi; }
                    sv = ns;
                }
                if (l15 == 0) {   // unique writer per m (same thread every nt)
                    int ml = w * 32 + i * 16 + quad * 4 + reg;
                    float sb = st_best[ml], ss = st_sec[ml]; int si = st_idx[ml];
                    float ns = fminf(fminf(ss, sv), fmaxf(sb, bv));
                    if (bv < sb || (bv == sb && bi < si)) { st_best[ml] = bv; st_idx[ml] = bi; }
                    st_sec[ml] = ns;
                }
            }
    }

    __syncthreads();
    if (tid < 128) {
        int n = m0 + tid;
        float bv = st_best[tid], sv = st_sec[tid];
        int bi = st_idx[tid];
        s_idx[n] = bi;
        out_s[n] = (float)bi;
        if (sv - bv < TAU) { int p = atomicAdd(flag_cnt, 1); flagged[p] = n; }
    }
    __syncthreads();
    for (int off = 64; off >= 1; off >>= 1) {
        if (tid < off && tid + off < 128) st_best[tid] += st_best[tid + off];
        __syncthreads();
    }
    if (tid == 0) atomicAdd(out_loss, st_best[0] * (1.0f / N_SAMPLES));
}

// ---------------- exact fp64 re-check of flagged near-tie samples ----------------
__global__ __launch_bounds__(256) void refine_kernel(
    const float* __restrict__ emb,
    const float* __restrict__ cen,
    const int* __restrict__ flag_cnt,
    const int* __restrict__ flagged,
    int* __restrict__ s_idx,
    float* __restrict__ out_s)
{
    __shared__ float e_sh[DIM];
    __shared__ double rvd[256];
    __shared__ int rid[256];
    const int t = threadIdx.x;
    const int cnt = *flag_cnt;
    for (int idx = blockIdx.x; idx < cnt; idx += gridDim.x) {
        int n = flagged[idx];
        __syncthreads();
        ((float2*)e_sh)[t] = ((const float2*)(emb + (size_t)n * DIM))[t];
        __syncthreads();
        double bestd = 1e300;
        int bestk = 0;
        #pragma unroll
        for (int j = 0; j < 4; ++j) {
            int k = t * 4 + j;
            const float* crow = cen + (size_t)k * DIM;
            double acc = 0.0;
            for (int d = 0; d < DIM; d += 4) {
                float4 cv = *(const float4*)(crow + d);
                double d0 = (double)e_sh[d + 0] - (double)cv.x;
                double d1 = (double)e_sh[d + 1] - (double)cv.y;
                double d2 = (double)e_sh[d + 2] - (double)cv.z;
                double d3 = (double)e_sh[d + 3] - (double)cv.w;
                acc += d0 * d0 + d1 * d1 + d2 * d2 + d3 * d3;
            }
            if (acc < bestd) { bestd = acc; bestk = k; }
        }
        rvd[t] = bestd; rid[t] = bestk;
        __syncthreads();
        for (int off = 128; off; off >>= 1) {
            if (t < off) {
                double v = rvd[t + off]; int ii = rid[t + off];
                if (v < rvd[t] || (v == rvd[t] && ii < rid[t])) { rvd[t] = v; rid[t] = ii; }
            }
            __syncthreads();
        }
        if (t == 0) { s_idx[n] = rid[0]; out_s[n] = (float)rid[0]; }
    }
}

// ---------------- histogram / scan / scatter ----------------
__global__ void hist_kernel(const int* __restrict__ s_idx, int* __restrict__ hist) {
    int n = blockIdx.x * blockDim.x + threadIdx.x;
    if (n < N_SAMPLES) atomicAdd(&hist[s_idx[n]], 1);
}

__global__ void scan_kernel(const int* __restrict__ hist,
                            int* __restrict__ offsets,
                            int* __restrict__ cursor,
                            const int* __restrict__ count_in,
                            float* __restrict__ out_count) {
    __shared__ int sbuf[K_CENT];
    int t = threadIdx.x;
    int v = hist[t];
    sbuf[t] = v;
    __syncthreads();
    for (int off = 1; off < K_CENT; off <<= 1) {
        int x = (t >= off) ? sbuf[t - off] : 0;
        __syncthreads();
        sbuf[t] += x;
        __syncthreads();
    }
    int incl = sbuf[t];
    offsets[t] = incl - v;
    cursor[t]  = incl - v;
    out_count[t] = (float)(count_in[t] + v);
    if (t == K_CENT - 1) offsets[K_CENT] = incl;
}

__global__ void scatter_kernel(const int* __restrict__ s_idx,
                               int* __restrict__ cursor,
                               int* __restrict__ order) {
    int n = blockIdx.x * blockDim.x + threadIdx.x;
    if (n < N_SAMPLES) {
        int pos = atomicAdd(&cursor[s_idx[n]], 1);
        order[pos] = n;
    }
}

// ---------------- balanced partial segment sums (fixed 32-entry slices) ----------------
__global__ __launch_bounds__(256) void gp_kernel(
    const float* __restrict__ emb,
    const int* __restrict__ s_idx,
    const int* __restrict__ order,
    float* __restrict__ accum,
    float* __restrict__ out_loss)
{
    __shared__ int s_n[32], s_c[32];
    const int t = threadIdx.x;
    const int base = blockIdx.x * 32;
    if (t < 32) { int n = order[base + t]; s_n[t] = n; s_c[t] = s_idx[n]; }
    __syncthreads();
    float ax = 0.f, ay = 0.f, ssq = 0.f;
    int cur = s_c[0];
    for (int r = 0; r < 32; ++r) {
        int n = s_n[r], c = s_c[r];
        if (c != cur) {   // uniform branch (shared value)
            atomicAdd(&accum[(size_t)cur * DIM + t * 2], ax);
            atomicAdd(&accum[(size_t)cur * DIM + t * 2 + 1], ay);
            ax = ay = 0.f; cur = c;
        }
        float2 e = *(const float2*)(emb + (size_t)n * DIM + t * 2);
        ax += e.x; ay += e.y;
        ssq += e.x * e.x + e.y * e.y;
    }
    atomicAdd(&accum[(size_t)cur * DIM + t * 2], ax);
    atomicAdd(&accum[(size_t)cur * DIM + t * 2 + 1], ay);

    for (int off = 32; off; off >>= 1) ssq += __shfl_down(ssq, off);
    __shared__ float wsum[4];
    if ((t & 63) == 0) wsum[t >> 6] = ssq;
    __syncthreads();
    if (t == 0)
        atomicAdd(out_loss, (wsum[0] + wsum[1] + wsum[2] + wsum[3]) * (1.0f / N_SAMPLES));
}

// ---------------- combine: out_centers = (cnt*c + accum) / (cnt + hist) ----------------
__global__ __launch_bounds__(256) void combine_kernel(
    const float* __restrict__ centers,
    const int* __restrict__ count_in,
    const int* __restrict__ hist,
    const float* __restrict__ accum,
    float* __restrict__ out_centers)
{
    int k = blockIdx.x, t = threadIdx.x;
    float cn = (float)count_in[k];
    float tot = cn + (float)hist[k];
    float2 c = *(const float2*)(centers + (size_t)k * DIM + t * 2);
    float2 a = *(const float2*)(accum   + (size_t)k * DIM + t * 2);
    float2 o;
    o.x = (cn * c.x + a.x) / tot;
    o.y = (cn * c.y + a.y) / tot;
    *(float2*)(out_centers + (size_t)k * DIM + t * 2) = o;
}

extern "C" void kernel_launch(void* const* d_in, const int* in_sizes, int n_in,
                              void* d_out, int out_size, void* d_ws, size_t ws_size,
                              hipStream_t stream) {
    const float* emb = (const float*)d_in[0];
    const float* cen = (const float*)d_in[1];
    const int*   cnt = (const int*)d_in[2];

    float* out = (float*)d_out;
    float* out_loss    = out;
    float* out_s       = out + 1;
    float* out_centers = out + 1 + N_SAMPLES;
    float* out_count   = out + 1 + N_SAMPLES + (size_t)K_CENT * DIM;

    int* wsi      = (int*)d_ws;
    int*   hist     = wsi;                       // [0, 1024)
    int*   offsets  = wsi + 1024;                // [1024, 2049) (+pad)
    int*   cursor   = wsi + 2064;                // [2064, 3088)
    int*   s_idx    = wsi + 4096;                // [4096, 69632)
    int*   order    = wsi + 69632;               // [69632, 135168)
    float* c2       = (float*)(wsi + 135168);    // [135168, 136192)
    int*   flag_cnt = wsi + 136192;              // [136192, 136256) (padded)
    int*   flagged  = wsi + 136256;              // [136256, 201792)
    // Bh needs K*D = 524288 shorts = 262144 ints (round-3 bug: was given 131072)
    unsigned short* Bh = (unsigned short*)(wsi + 201792);  // [201792, 463936)
    unsigned short* Bl = (unsigned short*)(wsi + 463936);  // [463936, 726080)
    // accum ALIASES Bh/Bl (dead after assign_mfma); zeroed after assign below
    float* accum    = (float*)(wsi + 201792);    // [201792, 726080)

    hipMemsetAsync(hist, 0, K_CENT * sizeof(int), stream);
    hipMemsetAsync(out_loss, 0, sizeof(float), stream);
    hipMemsetAsync(flag_cnt, 0, sizeof(int), stream);

    c2_kernel<<<K_CENT / 4, 256, 0, stream>>>(cen, c2);
    bsplit_kernel<<<512, 256, 0, stream>>>(cen, Bh, Bl);
    assign_mfma<<<N_SAMPLES / 128, 256, 0, stream>>>(emb, Bh, Bl, c2, out_loss, out_s,
                                                     s_idx, flag_cnt, flagged);
    // Bh/Bl no longer needed; reuse their space as the accumulation buffer
    hipMemsetAsync(accum, 0, (size_t)K_CENT * DIM * sizeof(float), stream);
    refine_kernel<<<256, 256, 0, stream>>>(emb, cen, flag_cnt, flagged, s_idx, out_s);
    hist_kernel<<<N_SAMPLES / 256, 256, 0, stream>>>(s_idx, hist);
    scan_kernel<<<1, K_CENT, 0, stream>>>(hist, offsets, cursor, cnt, out_count);
    scatter_kernel<<<N_SAMPLES / 256, 256, 0, stream>>>(s_idx, cursor, order);
    gp_kernel<<<N_SAMPLES / 32, 256, 0, stream>>>(emb, s_idx, order, accum, out_loss);
    combine_kernel<<<K_CENT, 256, 0, stream>>>(cen, cnt, hist, accum, out_centers);
}

// Round 5
// 727.442 us; speedup vs baseline: 2.8792x; 1.5247x over previous
//
#include <hip/hip_runtime.h>

#define N_SAMPLES 65536
#define K_CENT    1024
#define DIM       512
#define TAU 0.125f   // bf16-split dist error <= ~0.01 worst-case -> 10x+ margin

typedef __attribute__((ext_vector_type(8))) short  short8;
typedef __attribute__((ext_vector_type(4))) float  float4v;
typedef __attribute__((ext_vector_type(4))) unsigned short ushort4v;

__device__ inline unsigned short f2bf(float x) {           // RTNE fp32 -> bf16
    unsigned u = __builtin_bit_cast(unsigned, x);
    unsigned r = u + 0x7FFFu + ((u >> 16) & 1u);
    return (unsigned short)(r >> 16);
}
__device__ inline float bf2f(unsigned short h) {
    return __builtin_bit_cast(float, ((unsigned)h) << 16);
}

// ---------------- c2[k] = sum(centers[k]^2) ----------------
__global__ __launch_bounds__(256) void c2_kernel(const float* __restrict__ centers,
                                                 float* __restrict__ c2) {
    int wave = threadIdx.x >> 6, lane = threadIdx.x & 63;
    int k = blockIdx.x * 4 + wave;
    const float* row = centers + (size_t)k * DIM;
    float s = 0.f;
    #pragma unroll
    for (int base = 0; base < DIM; base += 256) {
        float4 v = *(const float4*)(row + base + lane * 4);
        s += v.x * v.x + v.y * v.y + v.z * v.z + v.w * v.w;
    }
    for (int off = 32; off; off >>= 1) s += __shfl_down(s, off);
    if (lane == 0) c2[k] = s;
}

// ---------------- split centers into bf16 hi/lo ----------------
__global__ __launch_bounds__(256) void bsplit_kernel(const float* __restrict__ cen,
                                                     unsigned short* __restrict__ Bh,
                                                     unsigned short* __restrict__ Bl) {
    int idx = blockIdx.x * 256 + threadIdx.x;   // float4 index; grid 512 covers 1024*512
    float4 v = ((const float4*)cen)[idx];
    float f[4] = {v.x, v.y, v.z, v.w};
    ushort4v h, l;
    #pragma unroll
    for (int e = 0; e < 4; ++e) {
        unsigned short hh = f2bf(f[e]);
        h[e] = hh;
        l[e] = f2bf(f[e] - bf2f(hh));
    }
    *(ushort4v*)(Bh + (size_t)idx * 4) = h;
    *(ushort4v*)(Bl + (size_t)idx * 4) = l;
}

// ---------------- MFMA assign: 128m x 512n per block, partial argmin out ----------------
#define LDSA 40   // padded A row stride (elements): 2-way bank alias = free
__global__ __launch_bounds__(256, 4) void assign_mfma(
    const float* __restrict__ A,            // embedded [N,D]
    const unsigned short* __restrict__ Bh,  // centers hi bf16 [K,D]
    const unsigned short* __restrict__ Bl,  // centers lo bf16 [K,D]
    const float* __restrict__ c2,
    float* __restrict__ pbest,              // [2][65536]
    float* __restrict__ psec,
    int* __restrict__ pidx)
{
    __shared__ unsigned short Ah[128 * LDSA];
    __shared__ unsigned short Al[128 * LDSA];
    __shared__ __align__(16) unsigned short Bt[8192];   // 16 KB: slot = p*512+q*128+r, 16B/slot
    __shared__ float st_best[128];
    __shared__ float st_sec[128];
    __shared__ int   st_idx[128];

    const int tid  = threadIdx.x;
    const int w    = tid >> 6;        // wave 0..3: rows w*32..w*32+31
    const int lane = tid & 63;
    const int quad = lane >> 4;
    const int l15  = lane & 15;
    const int mblk  = blockIdx.x & 511;
    const int chunk = blockIdx.x >> 9;      // temporal split: chunk0 blocks first -> L2-hot B
    const int m0   = mblk * 128;

    if (tid < 128) { st_best[tid] = 3.4e38f; st_sec[tid] = 3.4e38f; st_idx[tid] = 0; }

    const int r0 = tid >> 2, q = tid & 3;

    for (int nt = 0; nt < 4; ++nt) {
        const int n0 = chunk * 512 + nt * 128;
        float4v acc[16];
        #pragma unroll
        for (int z = 0; z < 16; ++z) acc[z] = (float4v){0.f, 0.f, 0.f, 0.f};

        for (int ks = 0; ks < 16; ++ks) {
            __syncthreads();
            // ---- stage A tile 128x32 fp32 -> bf16 hi/lo in LDS ----
            #pragma unroll
            for (int half = 0; half < 2; ++half) {
                int rr = r0 + half * 64;
                const float* src = A + (size_t)(m0 + rr) * DIM + ks * 32 + q * 8;
                float4 v0 = *(const float4*)src;
                float4 v1 = *(const float4*)(src + 4);
                float f[8] = {v0.x, v0.y, v0.z, v0.w, v1.x, v1.y, v1.z, v1.w};
                short8 hi, lo;
                #pragma unroll
                for (int e = 0; e < 8; ++e) {
                    unsigned short hh = f2bf(f[e]);
                    hi[e] = (short)hh;
                    lo[e] = (short)f2bf(f[e] - bf2f(hh));
                }
                *(short8*)&Ah[rr * LDSA + q * 8] = hi;
                *(short8*)&Al[rr * LDSA + q * 8] = lo;
            }
            // ---- stage B tile 128n x 32k (hi+lo bf16) into LDS, quad-major slots ----
            #pragma unroll
            for (int i = 0; i < 4; ++i) {
                int s = i * 256 + tid;             // slot 0..1023
                int p  = s >> 9;                   // plane: 0=hi 1=lo
                int sp = s & 511;
                int qq = sp >> 7, r = sp & 127;
                const unsigned short* src = (p ? Bl : Bh)
                    + (size_t)(n0 + r) * DIM + ks * 32 + qq * 8;
                *(short8*)&Bt[s * 8] = *(const short8*)src;
            }
            __syncthreads();

            // ---- A fragments from LDS ----
            short8 ah[2], al[2];
            #pragma unroll
            for (int i = 0; i < 2; ++i) {
                int row = w * 32 + i * 16 + l15;
                ah[i] = *(const short8*)&Ah[row * LDSA + quad * 8];
                al[i] = *(const short8*)&Al[row * LDSA + quad * 8];
            }
            // ---- B fragments from LDS; 3-term split MFMA ----
            #pragma unroll
            for (int j4 = 0; j4 < 8; ++j4) {
                short8 bh = *(const short8*)&Bt[(quad * 128 + j4 * 16 + l15) * 8];
                short8 bl = *(const short8*)&Bt[(512 + quad * 128 + j4 * 16 + l15) * 8];
                #pragma unroll
                for (int i = 0; i < 2; ++i) {
                    acc[i * 8 + j4] = __builtin_amdgcn_mfma_f32_16x16x32_bf16(
                        ah[i], bh, acc[i * 8 + j4], 0, 0, 0);
                    acc[i * 8 + j4] = __builtin_amdgcn_mfma_f32_16x16x32_bf16(
                        ah[i], bl, acc[i * 8 + j4], 0, 0, 0);
                    acc[i * 8 + j4] = __builtin_amdgcn_mfma_f32_16x16x32_bf16(
                        al[i], bh, acc[i * 8 + j4], 0, 0, 0);
                }
            }
        }

        // epilogue: dist = c2[n] - 2*cross; per-lane best over j, butterfly over l15
        float c2v[8];
        #pragma unroll
        for (int j = 0; j < 8; ++j) c2v[j] = c2[n0 + j * 16 + l15];
        #pragma unroll
        for (int i = 0; i < 2; ++i)
            #pragma unroll
            for (int reg = 0; reg < 4; ++reg) {
                float bv = 3.4e38f, sv = 3.4e38f; int bi = 0;
                #pragma unroll
                for (int j = 0; j < 8; ++j) {
                    float v = c2v[j] - 2.0f * acc[i * 8 + j][reg];
                    int n = n0 + j * 16 + l15;
                    if (v < bv) { sv = bv; bv = v; bi = n; }
                    else if (v < sv) sv = v;
                }
                #pragma unroll
                for (int mask = 1; mask < 16; mask <<= 1) {
                    float ob = __shfl_xor(bv, mask);
                    float os = __shfl_xor(sv, mask);
                    int   oi = __shfl_xor(bi, mask);
                    float ns = fminf(fminf(sv, os), fmaxf(bv, ob));
                    if (ob < bv || (ob == bv && oi < bi)) { bv = ob; bi = oi; }
                    sv = ns;
                }
                if (l15 == 0) {   // unique writer per m
                    int ml = w * 32 + i * 16 + quad * 4 + reg;
                    float sb = st_best[ml], ss = st_sec[ml]; int si = st_idx[ml];
                    float ns = fminf(fminf(ss, sv), fmaxf(sb, bv));
                    if (bv < sb || (bv == sb && bi < si)) { st_best[ml] = bv; st_idx[ml] = bi; }
                    st_sec[ml] = ns;
                }
            }
    }

    __syncthreads();
    if (tid < 128) {
        int m = m0 + tid;
        pbest[chunk * N_SAMPLES + m] = st_best[tid];
        psec [chunk * N_SAMPLES + m] = st_sec[tid];
        pidx [chunk * N_SAMPLES + m] = st_idx[tid];
    }
}

// ---------------- merge the 2 n-chunk partials: s, hist, loss, tie flags ----------------
__global__ __launch_bounds__(256) void merge_kernel(
    const float* __restrict__ pbest,
    const float* __restrict__ psec,
    const int* __restrict__ pidx,
    int* __restrict__ s_idx,
    float* __restrict__ out_s,
    int* __restrict__ hist,
    int* __restrict__ flag_cnt,
    int* __restrict__ flagged,
    float* __restrict__ out_loss)
{
    int m = blockIdx.x * 256 + threadIdx.x;
    float b0 = pbest[m], b1 = pbest[N_SAMPLES + m];
    float s0 = psec[m],  s1 = psec[N_SAMPLES + m];
    int   i0 = pidx[m],  i1 = pidx[N_SAMPLES + m];
    float bv, sv; int bi;
    if (b1 < b0) { bv = b1; bi = i1; sv = fminf(b0, s1); }   // tie -> chunk0 (lower idx)
    else         { bv = b0; bi = i0; sv = fminf(s0, b1); }
    s_idx[m] = bi;
    out_s[m] = (float)bi;
    atomicAdd(&hist[bi], 1);
    if (sv - bv < TAU) { int p = atomicAdd(flag_cnt, 1); flagged[p] = m; }

    float ls = bv;
    for (int off = 32; off; off >>= 1) ls += __shfl_down(ls, off);
    __shared__ float ws4[4];
    int lane = threadIdx.x & 63, wv = threadIdx.x >> 6;
    if (lane == 0) ws4[wv] = ls;
    __syncthreads();
    if (threadIdx.x == 0)
        atomicAdd(out_loss, (ws4[0] + ws4[1] + ws4[2] + ws4[3]) * (1.0f / N_SAMPLES));
}

// ---------------- exact fp64 re-check of flagged near-tie samples (+hist fixup) ----------------
__global__ __launch_bounds__(256) void refine_kernel(
    const float* __restrict__ emb,
    const float* __restrict__ cen,
    const int* __restrict__ flag_cnt,
    const int* __restrict__ flagged,
    int* __restrict__ s_idx,
    float* __restrict__ out_s,
    int* __restrict__ hist)
{
    __shared__ float e_sh[DIM];
    __shared__ double rvd[256];
    __shared__ int rid[256];
    const int t = threadIdx.x;
    const int cnt = *flag_cnt;
    for (int idx = blockIdx.x; idx < cnt; idx += gridDim.x) {
        int n = flagged[idx];
        __syncthreads();
        ((float2*)e_sh)[t] = ((const float2*)(emb + (size_t)n * DIM))[t];
        __syncthreads();
        double bestd = 1e300;
        int bestk = 0;
        #pragma unroll
        for (int j = 0; j < 4; ++j) {
            int k = t * 4 + j;
            const float* crow = cen + (size_t)k * DIM;
            double acc = 0.0;
            for (int d = 0; d < DIM; d += 4) {
                float4 cv = *(const float4*)(crow + d);
                double d0 = (double)e_sh[d + 0] - (double)cv.x;
                double d1 = (double)e_sh[d + 1] - (double)cv.y;
                double d2 = (double)e_sh[d + 2] - (double)cv.z;
                double d3 = (double)e_sh[d + 3] - (double)cv.w;
                acc += d0 * d0 + d1 * d1 + d2 * d2 + d3 * d3;
            }
            if (acc < bestd) { bestd = acc; bestk = k; }
        }
        rvd[t] = bestd; rid[t] = bestk;
        __syncthreads();
        for (int off = 128; off; off >>= 1) {
            if (t < off) {
                double v = rvd[t + off]; int ii = rid[t + off];
                if (v < rvd[t] || (v == rvd[t] && ii < rid[t])) { rvd[t] = v; rid[t] = ii; }
            }
            __syncthreads();
        }
        if (t == 0) {
            int old = s_idx[n], nw = rid[0];
            if (nw != old) {
                atomicSub(&hist[old], 1);
                atomicAdd(&hist[nw], 1);
                s_idx[n] = nw;
                out_s[n] = (float)nw;
            }
        }
    }
}

// ---------------- prefix sum over histogram ----------------
__global__ void scan_kernel(const int* __restrict__ hist,
                            int* __restrict__ offsets,
                            int* __restrict__ cursor,
                            const int* __restrict__ count_in,
                            float* __restrict__ out_count) {
    __shared__ int sbuf[K_CENT];
    int t = threadIdx.x;
    int v = hist[t];
    sbuf[t] = v;
    __syncthreads();
    for (int off = 1; off < K_CENT; off <<= 1) {
        int x = (t >= off) ? sbuf[t - off] : 0;
        __syncthreads();
        sbuf[t] += x;
        __syncthreads();
    }
    int incl = sbuf[t];
    offsets[t] = incl - v;
    cursor[t]  = incl - v;
    out_count[t] = (float)(count_in[t] + v);
    if (t == K_CENT - 1) offsets[K_CENT] = incl;
}

__global__ void scatter_kernel(const int* __restrict__ s_idx,
                               int* __restrict__ cursor,
                               int* __restrict__ order) {
    int n = blockIdx.x * blockDim.x + threadIdx.x;
    if (n < N_SAMPLES) {
        int pos = atomicAdd(&cursor[s_idx[n]], 1);
        order[pos] = n;
    }
}

// ---------------- balanced partial segment sums (fixed 64-entry slices) ----------------
__global__ __launch_bounds__(256) void gp_kernel(
    const float* __restrict__ emb,
    const int* __restrict__ s_idx,
    const int* __restrict__ order,
    float* __restrict__ accum,
    float* __restrict__ out_loss)
{
    __shared__ int s_n[64], s_c[64];
    const int t = threadIdx.x;
    const int base = blockIdx.x * 64;
    if (t < 64) { int n = order[base + t]; s_n[t] = n; s_c[t] = s_idx[n]; }
    __syncthreads();
    float ax = 0.f, ay = 0.f, ssq = 0.f;
    int cur = s_c[0];
    for (int r = 0; r < 64; ++r) {
        int n = s_n[r], c = s_c[r];
        if (c != cur) {   // uniform branch (shared value)
            atomicAdd(&accum[(size_t)cur * DIM + t * 2], ax);
            atomicAdd(&accum[(size_t)cur * DIM + t * 2 + 1], ay);
            ax = ay = 0.f; cur = c;
        }
        float2 e = *(const float2*)(emb + (size_t)n * DIM + t * 2);
        ax += e.x; ay += e.y;
        ssq += e.x * e.x + e.y * e.y;
    }
    atomicAdd(&accum[(size_t)cur * DIM + t * 2], ax);
    atomicAdd(&accum[(size_t)cur * DIM + t * 2 + 1], ay);

    for (int off = 32; off; off >>= 1) ssq += __shfl_down(ssq, off);
    __shared__ float wsum[4];
    if ((t & 63) == 0) wsum[t >> 6] = ssq;
    __syncthreads();
    if (t == 0)
        atomicAdd(out_loss, (wsum[0] + wsum[1] + wsum[2] + wsum[3]) * (1.0f / N_SAMPLES));
}

// ---------------- combine: out_centers = (cnt*c + accum) / (cnt + hist) ----------------
__global__ __launch_bounds__(256) void combine_kernel(
    const float* __restrict__ centers,
    const int* __restrict__ count_in,
    const int* __restrict__ hist,
    const float* __restrict__ accum,
    float* __restrict__ out_centers)
{
    int k = blockIdx.x, t = threadIdx.x;
    float cn = (float)count_in[k];
    float tot = cn + (float)hist[k];
    float2 c = *(const float2*)(centers + (size_t)k * DIM + t * 2);
    float2 a = *(const float2*)(accum   + (size_t)k * DIM + t * 2);
    float2 o;
    o.x = (cn * c.x + a.x) / tot;
    o.y = (cn * c.y + a.y) / tot;
    *(float2*)(out_centers + (size_t)k * DIM + t * 2) = o;
}

extern "C" void kernel_launch(void* const* d_in, const int* in_sizes, int n_in,
                              void* d_out, int out_size, void* d_ws, size_t ws_size,
                              hipStream_t stream) {
    const float* emb = (const float*)d_in[0];
    const float* cen = (const float*)d_in[1];
    const int*   cnt = (const int*)d_in[2];

    float* out = (float*)d_out;
    float* out_loss    = out;
    float* out_s       = out + 1;
    float* out_centers = out + 1 + N_SAMPLES;
    float* out_count   = out + 1 + N_SAMPLES + (size_t)K_CENT * DIM;

    int* wsi = (int*)d_ws;
    int*   hist     = wsi;                       // [0, 1024)
    int*   offsets  = wsi + 1024;                // [1024, 2049) +pad
    int*   cursor   = wsi + 2064;                // [2064, 3088)
    int*   s_idx    = wsi + 4096;                // [4096, 69632)
    float* c2       = (float*)(wsi + 69632);     // [69632, 70656)
    int*   flag_cnt = wsi + 70656;               // [70656, 70720) padded
    int*   flagged  = wsi + 70720;               // [70720, 136256)
    float* pbest    = (float*)(wsi + 136256);    // [136256, 267328)  2 x 65536
    float* psec     = (float*)(wsi + 267328);    // [267328, 398400)
    int*   pidx     = wsi + 398400;              // [398400, 529472)
    unsigned short* Bh = (unsigned short*)(wsi + 529472);  // [529472, 791616)
    unsigned short* Bl = (unsigned short*)(wsi + 791616);  // [791616, 1053760)
    // aliases (lifetimes disjoint):
    int*   order    = wsi + 136256;              // aliases pbest (dead after merge)
    float* accum    = (float*)(wsi + 529472);    // aliases Bh/Bl (dead after assign)

    hipMemsetAsync(hist, 0, K_CENT * sizeof(int), stream);
    hipMemsetAsync(out_loss, 0, sizeof(float), stream);
    hipMemsetAsync(flag_cnt, 0, sizeof(int), stream);

    c2_kernel<<<K_CENT / 4, 256, 0, stream>>>(cen, c2);
    bsplit_kernel<<<512, 256, 0, stream>>>(cen, Bh, Bl);
    assign_mfma<<<1024, 256, 0, stream>>>(emb, Bh, Bl, c2, pbest, psec, pidx);
    merge_kernel<<<N_SAMPLES / 256, 256, 0, stream>>>(pbest, psec, pidx, s_idx, out_s,
                                                      hist, flag_cnt, flagged, out_loss);
    // Bh/Bl dead; reuse as accumulation buffer
    hipMemsetAsync(accum, 0, (size_t)K_CENT * DIM * sizeof(float), stream);
    refine_kernel<<<256, 256, 0, stream>>>(emb, cen, flag_cnt, flagged, s_idx, out_s, hist);
    scan_kernel<<<1, K_CENT, 0, stream>>>(hist, offsets, cursor, cnt, out_count);
    scatter_kernel<<<N_SAMPLES / 256, 256, 0, stream>>>(s_idx, cursor, order);
    gp_kernel<<<N_SAMPLES / 64, 256, 0, stream>>>(emb, s_idx, order, accum, out_loss);
    combine_kernel<<<K_CENT, 256, 0, stream>>>(cen, cnt, hist, accum, out_centers);
}